// Round 21
// baseline (125.439 us; speedup 1.0000x reference)
//
#include <hip/hip_runtime.h>
#include <hip/hip_bf16.h>

#define C_DIM 1024
#define HEADS 16

typedef __bf16 bf16x8 __attribute__((ext_vector_type(8)));
typedef float f32x4 __attribute__((ext_vector_type(4)));

// round-to-nearest-even f32 -> bf16 (bit pattern)
static __device__ __forceinline__ unsigned short f2bf(float f) {
  unsigned int u = __builtin_bit_cast(unsigned int, f);
  u += 0x7FFFu + ((u >> 16) & 1u);
  return (unsigned short)(u >> 16);
}

static __device__ __forceinline__ float bf2f(unsigned short u) {
  unsigned int v = ((unsigned int)u) << 16;
  return __builtin_bit_cast(float, v);
}

// 2^x. libm exp2f — the raw __builtin_amdgcn_exp2f FAILED correctness in
// round 17 (absmax 4.16); do not substitute it back.
static __device__ __forceinline__ float fast_exp2(float x) {
  return exp2f(x);
}

// async global->LDS 16B (wave-uniform LDS base + lane*16; per-lane global src)
static __device__ __forceinline__ void glds16(const unsigned short* g,
                                              unsigned short* l) {
  __builtin_amdgcn_global_load_lds(
      (const __attribute__((address_space(1))) unsigned int*)g,
      (__attribute__((address_space(3))) unsigned int*)l, 16, 0, 0);
}

// ---------------- combined cast f32 -> bf16 (x, qkv_w) ---------------------
// NOTE: proj_w is NOT here — its destination slot lives inside the qkv-GEMM
// output region and must be cast AFTER that GEMM (round-11 bug). It is fused
// into the attn launch as tail blocks instead.
__global__ void cast2_kernel(const float* __restrict__ s0,
                             const float* __restrict__ s1,
                             unsigned short* __restrict__ d0,
                             unsigned short* __restrict__ d1, int n40) {
  int i = blockIdx.x * 256 + threadIdx.x;
  const float* s;
  unsigned short* d;
  if (i < n40) { s = s0; d = d0; }
  else { s = s1; d = d1; i -= n40; }
  float4 v = *reinterpret_cast<const float4*>(s + (size_t)i * 4);
  ushort4 o;
  o.x = f2bf(v.x); o.y = f2bf(v.y); o.z = f2bf(v.z); o.w = f2bf(v.w);
  *reinterpret_cast<ushort4*>(d + (size_t)i * 4) = o;
}

// ---------------- NT GEMM (m97 structure): C = A @ B^T + bias ----------------
// 1-D grid with XCD-bijective swizzle (requires gridDim.x % 8 == 0):
// wg = (bid&7)*(nwg/8) + bid>>3 gives each XCD a contiguous logical chunk
// (3 B-panels for qkv, 1 for proj) -> same-B-panel blocks share one L2.
template <bool BF16_OUT>
__global__ __launch_bounds__(256, 2) void gemm_nt(
    const unsigned short* __restrict__ A, const unsigned short* __restrict__ B,
    const float* __restrict__ bias, void* __restrict__ Cout,
    int Mtiles, int M, int N, int K) {
  __shared__ __align__(16) unsigned short As[128 * 64];
  __shared__ __align__(16) unsigned short Bs[128 * 64];
  const int nwg = gridDim.x;
  const int bid = blockIdx.x;
  const int wg = (bid & 7) * (nwg >> 3) + (bid >> 3);  // bijective (nwg%8==0)
  const int bm = (wg % Mtiles) * 128;
  const int bn = (wg / Mtiles) * 128;
  const int tid = threadIdx.x;
  const int lane = tid & 63;
  const int wave = tid >> 6;
  const int wm = wave >> 1, wn = wave & 1;
  const int g = lane >> 4, r = lane & 15;

  f32x4 acc[4][4] = {};

  for (int k0 = 0; k0 < K; k0 += 64) {
    __syncthreads();
#pragma unroll
    for (int i = 0; i < 4; ++i) {
      int cb = i * 256 + wave * 64;     // wave-uniform chunk base
      int c = cb + lane;                // 16B chunk index
      int row = c >> 3, col = (c & 7) * 8;
      glds16(&A[(size_t)(bm + row) * K + k0 + col], &As[cb * 8]);
      glds16(&B[(size_t)(bn + row) * K + k0 + col], &Bs[cb * 8]);
    }
    __syncthreads();   // drains vmcnt before frag reads

    bf16x8 af[4][2], bf[4][2];
#pragma unroll
    for (int m = 0; m < 4; ++m) {
      af[m][0] = *reinterpret_cast<const bf16x8*>(&As[(wm * 64 + m * 16 + r) * 64 + g * 8]);
      af[m][1] = *reinterpret_cast<const bf16x8*>(&As[(wm * 64 + m * 16 + r) * 64 + 32 + g * 8]);
    }
#pragma unroll
    for (int n = 0; n < 4; ++n) {
      bf[n][0] = *reinterpret_cast<const bf16x8*>(&Bs[(wn * 64 + n * 16 + r) * 64 + g * 8]);
      bf[n][1] = *reinterpret_cast<const bf16x8*>(&Bs[(wn * 64 + n * 16 + r) * 64 + 32 + g * 8]);
    }
#pragma unroll
    for (int m = 0; m < 4; ++m)
#pragma unroll
      for (int n = 0; n < 4; ++n) {
        acc[m][n] = __builtin_amdgcn_mfma_f32_16x16x32_bf16(af[m][0], bf[n][0], acc[m][n], 0, 0, 0);
        acc[m][n] = __builtin_amdgcn_mfma_f32_16x16x32_bf16(af[m][1], bf[n][1], acc[m][n], 0, 0, 0);
      }
  }

#pragma unroll
  for (int m = 0; m < 4; ++m) {
    int row0 = bm + wm * 64 + m * 16 + g * 4;
#pragma unroll
    for (int n = 0; n < 4; ++n) {
      int col = bn + wn * 64 + n * 16 + r;
      float bv = bias[col];
#pragma unroll
      for (int rr = 0; rr < 4; ++rr) {
        float v = acc[m][n][rr] + bv;
        if (BF16_OUT)
          reinterpret_cast<unsigned short*>(Cout)[(size_t)(row0 + rr) * N + col] = f2bf(v);
        else
          reinterpret_cast<float*>(Cout)[(size_t)(row0 + rr) * N + col] = v;
      }
    }
  }
}

// ---------------- prep: LN(q,k)+pack  AND  V transpose+permute -------------
// blockIdx < nLN: ln_pack for token bid (q pre-scaled by D^-0.5*log2(e)).
// blockIdx >= nLN: transpose v-cols of qkv into VT[B][H][D][P], position p
// within each 64-key tile holds key pi(p)=16*(2*(p>>5)+((p>>2)&1))
// +4*((p>>3)&3)+(p&3) — matches attn's in-register P pack.
__global__ __launch_bounds__(256) void prep_kernel(
    const unsigned short* __restrict__ qkv, const float* __restrict__ qg,
    const float* __restrict__ qb, const float* __restrict__ kg,
    const float* __restrict__ kb, unsigned short* __restrict__ Q,
    unsigned short* __restrict__ Ko, unsigned short* __restrict__ VT,
    int nLN) {
  __shared__ __align__(16) unsigned short tile[64][68];
  __shared__ float red[4][4];
  const int bid = blockIdx.x;
  const int tid = threadIdx.x;

  if (bid < nLN) {
    const int t = bid;
    const int b = t >> 10, n = t & 1023;
    const int lane = tid & 63, wave = tid >> 6;
    const unsigned short* row = qkv + (size_t)t * 3072;
    ushort4 qu = *reinterpret_cast<const ushort4*>(row + tid * 4);
    ushort4 ku = *reinterpret_cast<const ushort4*>(row + 1024 + tid * 4);
    float q0 = bf2f(qu.x), q1 = bf2f(qu.y), q2 = bf2f(qu.z), q3 = bf2f(qu.w);
    float k0 = bf2f(ku.x), k1 = bf2f(ku.y), k2 = bf2f(ku.z), k3 = bf2f(ku.w);

    float qs = q0 + q1 + q2 + q3;
    float qss = q0 * q0 + q1 * q1 + q2 * q2 + q3 * q3;
    float ks = k0 + k1 + k2 + k3;
    float kss = k0 * k0 + k1 * k1 + k2 * k2 + k3 * k3;
#pragma unroll
    for (int m = 1; m < 64; m <<= 1) {
      qs += __shfl_xor(qs, m);
      qss += __shfl_xor(qss, m);
      ks += __shfl_xor(ks, m);
      kss += __shfl_xor(kss, m);
    }
    if (lane == 0) {
      red[wave][0] = qs; red[wave][1] = qss; red[wave][2] = ks; red[wave][3] = kss;
    }
    __syncthreads();
    qs = red[0][0] + red[1][0] + red[2][0] + red[3][0];
    qss = red[0][1] + red[1][1] + red[2][1] + red[3][1];
    ks = red[0][2] + red[1][2] + red[2][2] + red[3][2];
    kss = red[0][3] + red[1][3] + red[2][3] + red[3][3];
    const float inv = 1.0f / 1024.0f;
    float qmu = qs * inv, kmu = ks * inv;
    float qrs = rsqrtf(qss * inv - qmu * qmu + 1e-5f);
    float krs = rsqrtf(kss * inv - kmu * kmu + 1e-5f);

    int c0 = tid * 4;
    float4 qg4 = *reinterpret_cast<const float4*>(qg + c0);
    float4 qb4 = *reinterpret_cast<const float4*>(qb + c0);
    float4 kg4 = *reinterpret_cast<const float4*>(kg + c0);
    float4 kb4 = *reinterpret_cast<const float4*>(kb + c0);
    int h = c0 >> 6, d = c0 & 63;
    size_t off = (((size_t)(b * HEADS + h)) * 1024 + n) * 64 + d;
    ushort4 qo, ko;
    const float QS = 0.125f * 1.44269504f;  // D^-0.5 * log2(e)
    qo.x = f2bf(((q0 - qmu) * qrs * qg4.x + qb4.x) * QS);
    qo.y = f2bf(((q1 - qmu) * qrs * qg4.y + qb4.y) * QS);
    qo.z = f2bf(((q2 - qmu) * qrs * qg4.z + qb4.z) * QS);
    qo.w = f2bf(((q3 - qmu) * qrs * qg4.w + qb4.w) * QS);
    ko.x = f2bf((k0 - kmu) * krs * kg4.x + kb4.x);
    ko.y = f2bf((k1 - kmu) * krs * kg4.y + kb4.y);
    ko.z = f2bf((k2 - kmu) * krs * kg4.z + kb4.z);
    ko.w = f2bf((k3 - kmu) * krs * kg4.w + kb4.w);
    *reinterpret_cast<ushort4*>(Q + off) = qo;
    *reinterpret_cast<ushort4*>(Ko + off) = ko;
  } else {
    const int idx0 = bid - nLN;
    const int bh = idx0 >> 4, nt = idx0 & 15;
    const int b = bh >> 4, h = bh & 15;
    unsigned short* dst = VT + (size_t)bh * 65536 + nt * 64;
#pragma unroll
    for (int i = 0; i < 4; ++i) {
      int idx = i * 256 + tid;            // 1024 = 64 rows x 16 chunks
      int row = idx >> 4, c4 = (idx & 15) * 4;
      int t = b * 1024 + nt * 64 + row;
      *reinterpret_cast<ushort4*>(&tile[row][c4]) =
          *reinterpret_cast<const ushort4*>(&qkv[(size_t)t * 3072 + 2048 + h * 64 + c4]);
    }
    __syncthreads();
#pragma unroll
    for (int i = 0; i < 4; ++i) {
      int idx = i * 256 + tid;
      int d = idx >> 4, p = (idx & 15) * 4;
      int key0 = 16 * (2 * (p >> 5) + ((p >> 2) & 1)) + 4 * ((p >> 3) & 3);
      ushort4 o;
      o.x = tile[key0][d]; o.y = tile[key0 + 1][d];
      o.z = tile[key0 + 2][d]; o.w = tile[key0 + 3][d];
      *reinterpret_cast<ushort4*>(&dst[(size_t)d * 1024 + p]) = o;
    }
  }
}

// ---------------- flash attention: 3-buffer counted-vmcnt pipeline ---------
// 1-D grid: blk = qb*64 + bh  (blk%8 == bh%8 -> same-head blocks share XCD).
// 4 waves; wave = 16 q rows. S^T = mfma(K,Q); softmax in-register (per-lane
// local max + deferred rescale, per-lane partial sum reduced once at end).
// K/V^T tiles triple-buffered in LDS; tile T+2 staged while computing T;
// end-of-iter: sched_barrier(0) + s_waitcnt vmcnt(4) (tile T+1 resident,
// T+2 still in flight — never drains to 0) + raw s_barrier. Per-wave STAGE
// = 4 glds; FIFO vmcnt semantics make vmcnt(4) drain exactly tile T+1.
// Tail blocks (blk >= nAttn) cast proj_w.
__global__ __launch_bounds__(256, 4) void attn_kernel(
    const unsigned short* __restrict__ Q, const unsigned short* __restrict__ K,
    const unsigned short* __restrict__ VT, unsigned short* __restrict__ O,
    int nAttn, const float* __restrict__ pw, unsigned short* __restrict__ pwb) {
  __shared__ __align__(16) unsigned short KL[3][4096];
  __shared__ __align__(16) unsigned short VL[3][4096];
  const int blk = blockIdx.x;
  if (blk >= nAttn) {
    int i = (blk - nAttn) * 256 + threadIdx.x;
    float4 v = *reinterpret_cast<const float4*>(pw + (size_t)i * 4);
    ushort4 o;
    o.x = f2bf(v.x); o.y = f2bf(v.y); o.z = f2bf(v.z); o.w = f2bf(v.w);
    *reinterpret_cast<ushort4*>(pwb + (size_t)i * 4) = o;
    return;
  }
  const int bh = blk & 63;
  const int qb = blk >> 6;
  const int tid = threadIdx.x;
  const int lane = tid & 63, wave = tid >> 6;
  const int g = lane >> 4, r = lane & 15;
  const unsigned short* Qh = Q + (size_t)bh * 65536;
  const unsigned short* Kh = K + (size_t)bh * 65536;
  const unsigned short* Vth = VT + (size_t)bh * 65536;
  const int q0 = qb * 64 + wave * 16;

  // B-frag: Q[qrow = q0 + r][d = 8g+i (+32)]
  bf16x8 bq0 = *reinterpret_cast<const bf16x8*>(&Qh[(q0 + r) * 64 + g * 8]);
  bf16x8 bq1 = *reinterpret_cast<const bf16x8*>(&Qh[(q0 + r) * 64 + 32 + g * 8]);

  f32x4 ao[4] = {};
  float mreg = -1e30f;   // running max for qrow r (consistent across its 4 lanes)
  float lsum = 0.f;      // PER-LANE partial row sum (reduced once at the end)

  // stage K/V^T tile kt into buffer b: 4 glds per wave (2 K + 2 V)
  auto STAGE = [&](int b, int kt) {
#pragma unroll
    for (int t = 0; t < 2; ++t) {
      int cb = (wave * 2 + t) * 64;          // wave-uniform chunk base
      int i = cb + lane;                     // chunk 0..511
      int row = i >> 3, pcol = i & 7;
      int lc = pcol ^ (row & 7);             // inverse-swizzled logical col
      glds16(Kh + (size_t)(kt + row) * 64 + lc * 8, &KL[b][cb * 8]);
      glds16(Vth + (size_t)row * 1024 + kt + lc * 8, &VL[b][cb * 8]);
    }
  };

  // prologue: tiles 0 and 1 in flight; wait tile 0 (4 of tile 1 outstanding)
  STAGE(0, 0);
  STAGE(1, 64);
  asm volatile("s_waitcnt vmcnt(4)" ::: "memory");
  __builtin_amdgcn_s_barrier();
  int cur = 0;

  for (int kt = 0; kt < 1024; kt += 64) {
    const int T = kt >> 6;
    if (T + 2 < 16) {
      int nb = cur + 2;
      if (nb >= 3) nb -= 3;
      STAGE(nb, kt + 128);
    }
    const unsigned short* KB = KL[cur];
    const unsigned short* VB = VL[cur];
    const int sw = r & 7;

    // A-frag from LDS: K[key = kt+16j+r][d = 8g+i (+32)], swizzled cols
    f32x4 s[4];
    __builtin_amdgcn_s_setprio(1);
#pragma unroll
    for (int j = 0; j < 4; ++j) {
      const int row = 16 * j + r;
      bf16x8 k0 = *reinterpret_cast<const bf16x8*>(&KB[row * 64 + (g ^ sw) * 8]);
      bf16x8 k1 = *reinterpret_cast<const bf16x8*>(&KB[row * 64 + ((4 + g) ^ sw) * 8]);
      f32x4 t = {};
      t = __builtin_amdgcn_mfma_f32_16x16x32_bf16(k0, bq0, t, 0, 0, 0);
      t = __builtin_amdgcn_mfma_f32_16x16x32_bf16(k1, bq1, t, 0, 0, 0);
      s[j] = t;
    }
    __builtin_amdgcn_s_setprio(0);
    // ---- softmax for qrow r: per-lane local max (no cross-lane in steady) --
    float a0 = fmaxf(fmaxf(s[0][0], s[0][1]), s[0][2]);
    float a1 = fmaxf(fmaxf(s[0][3], s[1][0]), s[1][1]);
    float a2 = fmaxf(fmaxf(s[1][2], s[1][3]), s[2][0]);
    float a3 = fmaxf(fmaxf(s[2][1], s[2][2]), s[2][3]);
    float a4 = fmaxf(fmaxf(s[3][0], s[3][1]), s[3][2]);
    float v = fmaxf(fmaxf(fmaxf(a0, a1), fmaxf(a2, a3)), fmaxf(a4, s[3][3]));
    // defer-max guard: __all over the wave covers all 4 lanes of every row
    if (!__all((int)(v - mreg <= 8.0f))) {
      float vt = v;
      vt = fmaxf(vt, __shfl_xor(vt, 16));
      vt = fmaxf(vt, __shfl_xor(vt, 32));
      float mnew = fmaxf(mreg, vt);
      float fac = fast_exp2(mreg - mnew);
      mreg = mnew;
      lsum *= fac;
      float facr[4];
#pragma unroll
      for (int rr = 0; rr < 4; ++rr)
        facr[rr] = __shfl(fac, (lane & 48) | (4 * g + rr));
#pragma unroll
      for (int n = 0; n < 4; ++n)
#pragma unroll
        for (int rr = 0; rr < 4; ++rr) ao[n][rr] *= facr[rr];
    }
#pragma unroll
    for (int j = 0; j < 4; ++j)
#pragma unroll
      for (int rr = 0; rr < 4; ++rr) s[j][rr] = fast_exp2(s[j][rr] - mreg);
    lsum += ((s[0][0] + s[0][1]) + (s[0][2] + s[0][3])) +
            ((s[1][0] + s[1][1]) + (s[1][2] + s[1][3])) +
            ((s[2][0] + s[2][1]) + (s[2][2] + s[2][3])) +
            ((s[3][0] + s[3][1]) + (s[3][2] + s[3][3]));
    // ---- pack P into PV A-frag (position p holds key pi(p), matching VT) --
    uint4 u0, u1;
    asm("v_cvt_pk_bf16_f32 %0, %1, %2" : "=v"(u0.x) : "v"(s[0][0]), "v"(s[0][1]));
    asm("v_cvt_pk_bf16_f32 %0, %1, %2" : "=v"(u0.y) : "v"(s[0][2]), "v"(s[0][3]));
    asm("v_cvt_pk_bf16_f32 %0, %1, %2" : "=v"(u0.z) : "v"(s[1][0]), "v"(s[1][1]));
    asm("v_cvt_pk_bf16_f32 %0, %1, %2" : "=v"(u0.w) : "v"(s[1][2]), "v"(s[1][3]));
    asm("v_cvt_pk_bf16_f32 %0, %1, %2" : "=v"(u1.x) : "v"(s[2][0]), "v"(s[2][1]));
    asm("v_cvt_pk_bf16_f32 %0, %1, %2" : "=v"(u1.y) : "v"(s[2][2]), "v"(s[2][3]));
    asm("v_cvt_pk_bf16_f32 %0, %1, %2" : "=v"(u1.z) : "v"(s[3][0]), "v"(s[3][1]));
    asm("v_cvt_pk_bf16_f32 %0, %1, %2" : "=v"(u1.w) : "v"(s[3][2]), "v"(s[3][3]));
    bf16x8 ap0 = __builtin_bit_cast(bf16x8, u0);
    bf16x8 ap1 = __builtin_bit_cast(bf16x8, u1);
    // ---- O += P @ V from LDS: VT[d-row n*16+r][key 8g+i (+32)], swizzled --
    __builtin_amdgcn_s_setprio(1);
#pragma unroll
    for (int n = 0; n < 4; ++n) {
      const int row = n * 16 + r;
      bf16x8 v0 = *reinterpret_cast<const bf16x8*>(&VB[row * 64 + (g ^ sw) * 8]);
      bf16x8 v1 = *reinterpret_cast<const bf16x8*>(&VB[row * 64 + ((4 + g) ^ sw) * 8]);
      ao[n] = __builtin_amdgcn_mfma_f32_16x16x32_bf16(ap0, v0, ao[n], 0, 0, 0);
      ao[n] = __builtin_amdgcn_mfma_f32_16x16x32_bf16(ap1, v1, ao[n], 0, 0, 0);
    }
    __builtin_amdgcn_s_setprio(0);
    // pin all prior LDS reads (rule #18), then counted wait: tile T+1 must be
    // resident; tile T+2's 4 loads stay in flight (never drain to 0 mid-loop)
    __builtin_amdgcn_sched_barrier(0);
    if (T + 2 < 16)
      asm volatile("s_waitcnt vmcnt(4)" ::: "memory");
    else
      asm volatile("s_waitcnt vmcnt(0)" ::: "memory");
    __builtin_amdgcn_s_barrier();
    cur = (cur + 1 == 3) ? 0 : cur + 1;
  }

  // final cross-lane row-sum reduction (once, not per tile)
  float lreg = lsum;
  lreg += __shfl_xor(lreg, 16);
  lreg += __shfl_xor(lreg, 32);

  const int b = bh >> 4, h = bh & 15;
  float lr[4];
#pragma unroll
  for (int rr = 0; rr < 4; ++rr)
    lr[rr] = 1.0f / __shfl(lreg, (lane & 48) | (4 * g + rr));
#pragma unroll
  for (int n = 0; n < 4; ++n)
#pragma unroll
    for (int rr = 0; rr < 4; ++rr) {
      int tok = q0 + 4 * g + rr;
      O[(((size_t)(b * 1024 + tok)) * 16 + h) * 64 + n * 16 + r] =
          f2bf(ao[n][rr] * lr[rr]);
    }
}

// ---- sentinel: exfiltrate ws_size through absmax --------------------------
__global__ void sentinel_kernel(unsigned short* out, float v) {
  if (threadIdx.x == 0 && blockIdx.x == 0) out[0] = f2bf(v);
}

extern "C" void kernel_launch(void* const* d_in, const int* in_sizes, int n_in,
                              void* d_out, int out_size, void* d_ws, size_t ws_size,
                              hipStream_t stream) {
  const float* x      = (const float*)d_in[0];
  const float* qkv_w  = (const float*)d_in[1];
  const float* qkv_b  = (const float*)d_in[2];
  const float* q_g    = (const float*)d_in[3];
  const float* q_b    = (const float*)d_in[4];
  const float* k_g    = (const float*)d_in[5];
  const float* k_b    = (const float*)d_in[6];
  const float* proj_w = (const float*)d_in[7];
  const float* proj_b = (const float*)d_in[8];

  const int M = in_sizes[0] / C_DIM;  // tokens = B*N
  const int Bb = M / 1024;

  // ws = region A (qkv_bf, M*3072 shorts) + region B (Qb|Kb|VT slots).
  // Total 48 MiB at M=4096 (round-3-proven). Overlays & lifetimes:
  //  pre-GEMM:  x_bf -> Qb slot, qw_bf -> Kb slot (dead after qkv GEMM)
  //  post-GEMM: prep writes Qb,Kb,VT (region B; VT source = qkv v-cols in A)
  //  attn: reads region B, writes AO = A[0,M*1024); tail blocks cast proj_w
  //        into pw_bf = A[2M,3M)*1024 (qkv dead by then; AO disjoint).
  const size_t required = (size_t)M * 3072 * 2 + (size_t)3 * M * 1024 * 2;
  if (ws_size < required) {
    sentinel_kernel<<<1, 64, 0, stream>>>((unsigned short*)d_out, (float)ws_size);
    return;
  }

  unsigned short* qkv_bf = (unsigned short*)d_ws;               // region A
  unsigned short* Qb = qkv_bf + (size_t)M * 3072;               // region B
  unsigned short* Kb = Qb + (size_t)M * 1024;
  unsigned short* VTn = Kb + (size_t)M * 1024;                  // former Vb slot
  unsigned short* x_bf = Qb;                                    // overlay
  unsigned short* qw_bf = Kb;                                   // overlay (3M<=4M)
  unsigned short* AO = qkv_bf;                                  // overlay
  unsigned short* pw_bf = qkv_bf + (size_t)2 * M * 1024;        // overlay

  const int n4x = M * 1024 / 4;
  const int n4w1 = 3072 * 1024 / 4;
  const int n4w2 = 1024 * 1024 / 4;

  cast2_kernel<<<(n4x + n4w1) / 256, 256, 0, stream>>>(
      x, qkv_w, x_bf, qw_bf, n4x);

  gemm_nt<true><<<(M / 128) * (3072 / 128), 256, 0, stream>>>(
      x_bf, qw_bf, qkv_b, qkv_bf, M / 128, M, 3072, 1024);

  prep_kernel<<<M + Bb * HEADS * 16, 256, 0, stream>>>(
      qkv_bf, q_g, q_b, k_g, k_b, Qb, Kb, VTn, M);

  const int nAttn = Bb * HEADS * 16;
  attn_kernel<<<nAttn + n4w2 / 256, 256, 0, stream>>>(
      Qb, Kb, VTn, AO, nAttn, proj_w, pw_bf);

  gemm_nt<false><<<(M / 128) * (1024 / 128), 256, 0, stream>>>(
      AO, pw_bf, proj_b, (float*)d_out, M / 128, M, 1024, 1024);
}

// Round 22
// 116.788 us; speedup vs baseline: 1.0741x; 1.0741x over previous
//
#include <hip/hip_runtime.h>
#include <hip/hip_bf16.h>

#define C_DIM 1024
#define HEADS 16

typedef __bf16 bf16x8 __attribute__((ext_vector_type(8)));
typedef float f32x4 __attribute__((ext_vector_type(4)));

// round-to-nearest-even f32 -> bf16 (bit pattern)
static __device__ __forceinline__ unsigned short f2bf(float f) {
  unsigned int u = __builtin_bit_cast(unsigned int, f);
  u += 0x7FFFu + ((u >> 16) & 1u);
  return (unsigned short)(u >> 16);
}

static __device__ __forceinline__ float bf2f(unsigned short u) {
  unsigned int v = ((unsigned int)u) << 16;
  return __builtin_bit_cast(float, v);
}

// 2^x. libm exp2f — the raw __builtin_amdgcn_exp2f FAILED correctness in
// round 17 (absmax 4.16); do not substitute it back.
static __device__ __forceinline__ float fast_exp2(float x) {
  return exp2f(x);
}

// async global->LDS 16B (wave-uniform LDS base + lane*16; per-lane global src)
static __device__ __forceinline__ void glds16(const unsigned short* g,
                                              unsigned short* l) {
  __builtin_amdgcn_global_load_lds(
      (const __attribute__((address_space(1))) unsigned int*)g,
      (__attribute__((address_space(3))) unsigned int*)l, 16, 0, 0);
}

// ---------------- combined cast f32 -> bf16 (x, qkv_w) ---------------------
// NOTE: proj_w is NOT here — its destination slot lives inside the qkv-GEMM
// output region and must be cast AFTER that GEMM (round-11 bug). It is fused
// into the attn launch as tail blocks instead.
__global__ void cast2_kernel(const float* __restrict__ s0,
                             const float* __restrict__ s1,
                             unsigned short* __restrict__ d0,
                             unsigned short* __restrict__ d1, int n40) {
  int i = blockIdx.x * 256 + threadIdx.x;
  const float* s;
  unsigned short* d;
  if (i < n40) { s = s0; d = d0; }
  else { s = s1; d = d1; i -= n40; }
  float4 v = *reinterpret_cast<const float4*>(s + (size_t)i * 4);
  ushort4 o;
  o.x = f2bf(v.x); o.y = f2bf(v.y); o.z = f2bf(v.z); o.w = f2bf(v.w);
  *reinterpret_cast<ushort4*>(d + (size_t)i * 4) = o;
}

// ---------------- NT GEMM (m97 structure): C = A @ B^T + bias ----------------
// 1-D grid with XCD-bijective swizzle (requires gridDim.x % 8 == 0):
// wg = (bid&7)*(nwg/8) + bid>>3 gives each XCD a contiguous logical chunk
// (3 B-panels for qkv, 1 for proj) -> same-B-panel blocks share one L2.
template <bool BF16_OUT>
__global__ __launch_bounds__(256, 2) void gemm_nt(
    const unsigned short* __restrict__ A, const unsigned short* __restrict__ B,
    const float* __restrict__ bias, void* __restrict__ Cout,
    int Mtiles, int M, int N, int K) {
  __shared__ __align__(16) unsigned short As[128 * 64];
  __shared__ __align__(16) unsigned short Bs[128 * 64];
  const int nwg = gridDim.x;
  const int bid = blockIdx.x;
  const int wg = (bid & 7) * (nwg >> 3) + (bid >> 3);  // bijective (nwg%8==0)
  const int bm = (wg % Mtiles) * 128;
  const int bn = (wg / Mtiles) * 128;
  const int tid = threadIdx.x;
  const int lane = tid & 63;
  const int wave = tid >> 6;
  const int wm = wave >> 1, wn = wave & 1;
  const int g = lane >> 4, r = lane & 15;

  f32x4 acc[4][4] = {};

  for (int k0 = 0; k0 < K; k0 += 64) {
    __syncthreads();
#pragma unroll
    for (int i = 0; i < 4; ++i) {
      int cb = i * 256 + wave * 64;     // wave-uniform chunk base
      int c = cb + lane;                // 16B chunk index
      int row = c >> 3, col = (c & 7) * 8;
      glds16(&A[(size_t)(bm + row) * K + k0 + col], &As[cb * 8]);
      glds16(&B[(size_t)(bn + row) * K + k0 + col], &Bs[cb * 8]);
    }
    __syncthreads();   // drains vmcnt before frag reads

    bf16x8 af[4][2], bf[4][2];
#pragma unroll
    for (int m = 0; m < 4; ++m) {
      af[m][0] = *reinterpret_cast<const bf16x8*>(&As[(wm * 64 + m * 16 + r) * 64 + g * 8]);
      af[m][1] = *reinterpret_cast<const bf16x8*>(&As[(wm * 64 + m * 16 + r) * 64 + 32 + g * 8]);
    }
#pragma unroll
    for (int n = 0; n < 4; ++n) {
      bf[n][0] = *reinterpret_cast<const bf16x8*>(&Bs[(wn * 64 + n * 16 + r) * 64 + g * 8]);
      bf[n][1] = *reinterpret_cast<const bf16x8*>(&Bs[(wn * 64 + n * 16 + r) * 64 + 32 + g * 8]);
    }
#pragma unroll
    for (int m = 0; m < 4; ++m)
#pragma unroll
      for (int n = 0; n < 4; ++n) {
        acc[m][n] = __builtin_amdgcn_mfma_f32_16x16x32_bf16(af[m][0], bf[n][0], acc[m][n], 0, 0, 0);
        acc[m][n] = __builtin_amdgcn_mfma_f32_16x16x32_bf16(af[m][1], bf[n][1], acc[m][n], 0, 0, 0);
      }
  }

#pragma unroll
  for (int m = 0; m < 4; ++m) {
    int row0 = bm + wm * 64 + m * 16 + g * 4;
#pragma unroll
    for (int n = 0; n < 4; ++n) {
      int col = bn + wn * 64 + n * 16 + r;
      float bv = bias[col];
#pragma unroll
      for (int rr = 0; rr < 4; ++rr) {
        float v = acc[m][n][rr] + bv;
        if (BF16_OUT)
          reinterpret_cast<unsigned short*>(Cout)[(size_t)(row0 + rr) * N + col] = f2bf(v);
        else
          reinterpret_cast<float*>(Cout)[(size_t)(row0 + rr) * N + col] = v;
      }
    }
  }
}

// ---------------- prep: LN(q,k)+pack  AND  V transpose+permute -------------
// blockIdx < nLN: ln_pack for token bid (q pre-scaled by D^-0.5*log2(e)).
// blockIdx >= nLN: transpose v-cols of qkv into VT[B][H][D][P], position p
// within each 64-key tile holds key pi(p)=16*(2*(p>>5)+((p>>2)&1))
// +4*((p>>3)&3)+(p&3) — matches attn's in-register P pack.
__global__ __launch_bounds__(256) void prep_kernel(
    const unsigned short* __restrict__ qkv, const float* __restrict__ qg,
    const float* __restrict__ qb, const float* __restrict__ kg,
    const float* __restrict__ kb, unsigned short* __restrict__ Q,
    unsigned short* __restrict__ Ko, unsigned short* __restrict__ VT,
    int nLN) {
  __shared__ __align__(16) unsigned short tile[64][68];
  __shared__ float red[4][4];
  const int bid = blockIdx.x;
  const int tid = threadIdx.x;

  if (bid < nLN) {
    const int t = bid;
    const int b = t >> 10, n = t & 1023;
    const int lane = tid & 63, wave = tid >> 6;
    const unsigned short* row = qkv + (size_t)t * 3072;
    ushort4 qu = *reinterpret_cast<const ushort4*>(row + tid * 4);
    ushort4 ku = *reinterpret_cast<const ushort4*>(row + 1024 + tid * 4);
    float q0 = bf2f(qu.x), q1 = bf2f(qu.y), q2 = bf2f(qu.z), q3 = bf2f(qu.w);
    float k0 = bf2f(ku.x), k1 = bf2f(ku.y), k2 = bf2f(ku.z), k3 = bf2f(ku.w);

    float qs = q0 + q1 + q2 + q3;
    float qss = q0 * q0 + q1 * q1 + q2 * q2 + q3 * q3;
    float ks = k0 + k1 + k2 + k3;
    float kss = k0 * k0 + k1 * k1 + k2 * k2 + k3 * k3;
#pragma unroll
    for (int m = 1; m < 64; m <<= 1) {
      qs += __shfl_xor(qs, m);
      qss += __shfl_xor(qss, m);
      ks += __shfl_xor(ks, m);
      kss += __shfl_xor(kss, m);
    }
    if (lane == 0) {
      red[wave][0] = qs; red[wave][1] = qss; red[wave][2] = ks; red[wave][3] = kss;
    }
    __syncthreads();
    qs = red[0][0] + red[1][0] + red[2][0] + red[3][0];
    qss = red[0][1] + red[1][1] + red[2][1] + red[3][1];
    ks = red[0][2] + red[1][2] + red[2][2] + red[3][2];
    kss = red[0][3] + red[1][3] + red[2][3] + red[3][3];
    const float inv = 1.0f / 1024.0f;
    float qmu = qs * inv, kmu = ks * inv;
    float qrs = rsqrtf(qss * inv - qmu * qmu + 1e-5f);
    float krs = rsqrtf(kss * inv - kmu * kmu + 1e-5f);

    int c0 = tid * 4;
    float4 qg4 = *reinterpret_cast<const float4*>(qg + c0);
    float4 qb4 = *reinterpret_cast<const float4*>(qb + c0);
    float4 kg4 = *reinterpret_cast<const float4*>(kg + c0);
    float4 kb4 = *reinterpret_cast<const float4*>(kb + c0);
    int h = c0 >> 6, d = c0 & 63;
    size_t off = (((size_t)(b * HEADS + h)) * 1024 + n) * 64 + d;
    ushort4 qo, ko;
    const float QS = 0.125f * 1.44269504f;  // D^-0.5 * log2(e)
    qo.x = f2bf(((q0 - qmu) * qrs * qg4.x + qb4.x) * QS);
    qo.y = f2bf(((q1 - qmu) * qrs * qg4.y + qb4.y) * QS);
    qo.z = f2bf(((q2 - qmu) * qrs * qg4.z + qb4.z) * QS);
    qo.w = f2bf(((q3 - qmu) * qrs * qg4.w + qb4.w) * QS);
    ko.x = f2bf((k0 - kmu) * krs * kg4.x + kb4.x);
    ko.y = f2bf((k1 - kmu) * krs * kg4.y + kb4.y);
    ko.z = f2bf((k2 - kmu) * krs * kg4.z + kb4.z);
    ko.w = f2bf((k3 - kmu) * krs * kg4.w + kb4.w);
    *reinterpret_cast<ushort4*>(Q + off) = qo;
    *reinterpret_cast<ushort4*>(Ko + off) = ko;
  } else {
    const int idx0 = bid - nLN;
    const int bh = idx0 >> 4, nt = idx0 & 15;
    const int b = bh >> 4, h = bh & 15;
    unsigned short* dst = VT + (size_t)bh * 65536 + nt * 64;
#pragma unroll
    for (int i = 0; i < 4; ++i) {
      int idx = i * 256 + tid;            // 1024 = 64 rows x 16 chunks
      int row = idx >> 4, c4 = (idx & 15) * 4;
      int t = b * 1024 + nt * 64 + row;
      *reinterpret_cast<ushort4*>(&tile[row][c4]) =
          *reinterpret_cast<const ushort4*>(&qkv[(size_t)t * 3072 + 2048 + h * 64 + c4]);
    }
    __syncthreads();
#pragma unroll
    for (int i = 0; i < 4; ++i) {
      int idx = i * 256 + tid;
      int d = idx >> 4, p = (idx & 15) * 4;
      int key0 = 16 * (2 * (p >> 5) + ((p >> 2) & 1)) + 4 * ((p >> 3) & 3);
      ushort4 o;
      o.x = tile[key0][d]; o.y = tile[key0 + 1][d];
      o.z = tile[key0 + 2][d]; o.w = tile[key0 + 3][d];
      *reinterpret_cast<ushort4*>(&dst[(size_t)d * 1024 + p]) = o;
    }
  }
}

// ---------------- flash attention: LDS-staged K/V, swapped QK^T ------------
// 1-D grid: blk = qb*64 + bh  (blk%8 == bh%8 -> same-head blocks share XCD).
// 4 waves; wave = 16 q rows. S^T = mfma(K,Q): lane (g,r) holds
// s[j][rr] = S[key 16j+4g+rr][qrow r]; softmax fully in-register, exp2 units
// (libm exp2f). Steady state has ZERO cross-lane ops: per-lane local max
// guards defer-max via __all (rare branch does the true shfl-reduce), and
// the row-sum is a per-lane partial reduced once at the end.
// K and V^T 64-tiles in LDS, double-buffered, XOR-swizzled. Tail blocks
// (blk >= nAttn) cast proj_w (safe: attn writes AO = A[0,M*1024)).
__global__ __launch_bounds__(256, 4) void attn_kernel(
    const unsigned short* __restrict__ Q, const unsigned short* __restrict__ K,
    const unsigned short* __restrict__ VT, unsigned short* __restrict__ O,
    int nAttn, const float* __restrict__ pw, unsigned short* __restrict__ pwb) {
  __shared__ __align__(16) unsigned short KL[2][4096];
  __shared__ __align__(16) unsigned short VL[2][4096];
  const int blk = blockIdx.x;
  if (blk >= nAttn) {
    int i = (blk - nAttn) * 256 + threadIdx.x;
    float4 v = *reinterpret_cast<const float4*>(pw + (size_t)i * 4);
    ushort4 o;
    o.x = f2bf(v.x); o.y = f2bf(v.y); o.z = f2bf(v.z); o.w = f2bf(v.w);
    *reinterpret_cast<ushort4*>(pwb + (size_t)i * 4) = o;
    return;
  }
  const int bh = blk & 63;
  const int qb = blk >> 6;
  const int tid = threadIdx.x;
  const int lane = tid & 63, wave = tid >> 6;
  const int g = lane >> 4, r = lane & 15;
  const unsigned short* Qh = Q + (size_t)bh * 65536;
  const unsigned short* Kh = K + (size_t)bh * 65536;
  const unsigned short* Vth = VT + (size_t)bh * 65536;
  const int q0 = qb * 64 + wave * 16;

  // B-frag: Q[qrow = q0 + r][d = 8g+i (+32)]
  bf16x8 bq0 = *reinterpret_cast<const bf16x8*>(&Qh[(q0 + r) * 64 + g * 8]);
  bf16x8 bq1 = *reinterpret_cast<const bf16x8*>(&Qh[(q0 + r) * 64 + 32 + g * 8]);

  f32x4 ao[4] = {};
  float mreg = -1e30f;   // running max for qrow r (consistent across its 4 lanes)
  float lsum = 0.f;      // PER-LANE partial row sum (reduced once at the end)

  // stage K/V^T tile kt into buffer b: 512 chunks each, 2 glds/wave each
  auto STAGE = [&](int b, int kt) {
#pragma unroll
    for (int t = 0; t < 2; ++t) {
      int cb = (wave * 2 + t) * 64;          // wave-uniform chunk base
      int i = cb + lane;                     // chunk 0..511
      int row = i >> 3, pcol = i & 7;
      int lc = pcol ^ (row & 7);             // inverse-swizzled logical col
      glds16(Kh + (size_t)(kt + row) * 64 + lc * 8, &KL[b][cb * 8]);
      glds16(Vth + (size_t)row * 1024 + kt + lc * 8, &VL[b][cb * 8]);
    }
  };

  STAGE(0, 0);
  __syncthreads();
  int cur = 0;

  for (int kt = 0; kt < 1024; kt += 64) {
    if (kt + 64 < 1024) STAGE(cur ^ 1, kt + 64);
    const unsigned short* KB = KL[cur];
    const unsigned short* VB = VL[cur];
    const int sw = r & 7;

    // A-frag from LDS: K[key = kt+16j+r][d = 8g+i (+32)], swizzled cols
    f32x4 s[4];
    __builtin_amdgcn_s_setprio(1);
#pragma unroll
    for (int j = 0; j < 4; ++j) {
      const int row = 16 * j + r;
      bf16x8 k0 = *reinterpret_cast<const bf16x8*>(&KB[row * 64 + (g ^ sw) * 8]);
      bf16x8 k1 = *reinterpret_cast<const bf16x8*>(&KB[row * 64 + ((4 + g) ^ sw) * 8]);
      f32x4 t = {};
      t = __builtin_amdgcn_mfma_f32_16x16x32_bf16(k0, bq0, t, 0, 0, 0);
      t = __builtin_amdgcn_mfma_f32_16x16x32_bf16(k1, bq1, t, 0, 0, 0);
      s[j] = t;
    }
    __builtin_amdgcn_s_setprio(0);
    // ---- softmax for qrow r: per-lane local max (no cross-lane in steady) --
    float a0 = fmaxf(fmaxf(s[0][0], s[0][1]), s[0][2]);
    float a1 = fmaxf(fmaxf(s[0][3], s[1][0]), s[1][1]);
    float a2 = fmaxf(fmaxf(s[1][2], s[1][3]), s[2][0]);
    float a3 = fmaxf(fmaxf(s[2][1], s[2][2]), s[2][3]);
    float a4 = fmaxf(fmaxf(s[3][0], s[3][1]), s[3][2]);
    float v = fmaxf(fmaxf(fmaxf(a0, a1), fmaxf(a2, a3)), fmaxf(a4, s[3][3]));
    // defer-max guard: __all over the wave covers all 4 lanes of every row;
    // if every lane's LOCAL max is within 8 of mreg, so is the row max.
    if (!__all((int)(v - mreg <= 8.0f))) {
      // true cross-lane row max (rare path)
      float vt = v;
      vt = fmaxf(vt, __shfl_xor(vt, 16));
      vt = fmaxf(vt, __shfl_xor(vt, 32));
      float mnew = fmaxf(mreg, vt);
      float fac = fast_exp2(mreg - mnew);
      mreg = mnew;
      lsum *= fac;   // per-lane partial scales by its own row's factor
      float facr[4];
#pragma unroll
      for (int rr = 0; rr < 4; ++rr)
        facr[rr] = __shfl(fac, (lane & 48) | (4 * g + rr));
#pragma unroll
      for (int n = 0; n < 4; ++n)
#pragma unroll
        for (int rr = 0; rr < 4; ++rr) ao[n][rr] *= facr[rr];
    }
#pragma unroll
    for (int j = 0; j < 4; ++j)
#pragma unroll
      for (int rr = 0; rr < 4; ++rr) s[j][rr] = fast_exp2(s[j][rr] - mreg);
    lsum += ((s[0][0] + s[0][1]) + (s[0][2] + s[0][3])) +
            ((s[1][0] + s[1][1]) + (s[1][2] + s[1][3])) +
            ((s[2][0] + s[2][1]) + (s[2][2] + s[2][3])) +
            ((s[3][0] + s[3][1]) + (s[3][2] + s[3][3]));
    // ---- pack P into PV A-frag (position p holds key pi(p), matching VT) --
    uint4 u0, u1;
    asm("v_cvt_pk_bf16_f32 %0, %1, %2" : "=v"(u0.x) : "v"(s[0][0]), "v"(s[0][1]));
    asm("v_cvt_pk_bf16_f32 %0, %1, %2" : "=v"(u0.y) : "v"(s[0][2]), "v"(s[0][3]));
    asm("v_cvt_pk_bf16_f32 %0, %1, %2" : "=v"(u0.z) : "v"(s[1][0]), "v"(s[1][1]));
    asm("v_cvt_pk_bf16_f32 %0, %1, %2" : "=v"(u0.w) : "v"(s[1][2]), "v"(s[1][3]));
    asm("v_cvt_pk_bf16_f32 %0, %1, %2" : "=v"(u1.x) : "v"(s[2][0]), "v"(s[2][1]));
    asm("v_cvt_pk_bf16_f32 %0, %1, %2" : "=v"(u1.y) : "v"(s[2][2]), "v"(s[2][3]));
    asm("v_cvt_pk_bf16_f32 %0, %1, %2" : "=v"(u1.z) : "v"(s[3][0]), "v"(s[3][1]));
    asm("v_cvt_pk_bf16_f32 %0, %1, %2" : "=v"(u1.w) : "v"(s[3][2]), "v"(s[3][3]));
    bf16x8 ap0 = __builtin_bit_cast(bf16x8, u0);
    bf16x8 ap1 = __builtin_bit_cast(bf16x8, u1);
    // ---- O += P @ V from LDS: VT[d-row n*16+r][key 8g+i (+32)], swizzled --
    __builtin_amdgcn_s_setprio(1);
#pragma unroll
    for (int n = 0; n < 4; ++n) {
      const int row = n * 16 + r;
      bf16x8 v0 = *reinterpret_cast<const bf16x8*>(&VB[row * 64 + (g ^ sw) * 8]);
      bf16x8 v1 = *reinterpret_cast<const bf16x8*>(&VB[row * 64 + ((4 + g) ^ sw) * 8]);
      ao[n] = __builtin_amdgcn_mfma_f32_16x16x32_bf16(ap0, v0, ao[n], 0, 0, 0);
      ao[n] = __builtin_amdgcn_mfma_f32_16x16x32_bf16(ap1, v1, ao[n], 0, 0, 0);
    }
    __builtin_amdgcn_s_setprio(0);
    __syncthreads();
    cur ^= 1;
  }

  // final cross-lane row-sum reduction (once, not per tile)
  float lreg = lsum;
  lreg += __shfl_xor(lreg, 16);
  lreg += __shfl_xor(lreg, 32);

  const int b = bh >> 4, h = bh & 15;
  float lr[4];
#pragma unroll
  for (int rr = 0; rr < 4; ++rr)
    lr[rr] = 1.0f / __shfl(lreg, (lane & 48) | (4 * g + rr));
#pragma unroll
  for (int n = 0; n < 4; ++n)
#pragma unroll
    for (int rr = 0; rr < 4; ++rr) {
      int tok = q0 + 4 * g + rr;
      O[(((size_t)(b * 1024 + tok)) * 16 + h) * 64 + n * 16 + r] =
          f2bf(ao[n][rr] * lr[rr]);
    }
}

// ---- sentinel: exfiltrate ws_size through absmax --------------------------
__global__ void sentinel_kernel(unsigned short* out, float v) {
  if (threadIdx.x == 0 && blockIdx.x == 0) out[0] = f2bf(v);
}

extern "C" void kernel_launch(void* const* d_in, const int* in_sizes, int n_in,
                              void* d_out, int out_size, void* d_ws, size_t ws_size,
                              hipStream_t stream) {
  const float* x      = (const float*)d_in[0];
  const float* qkv_w  = (const float*)d_in[1];
  const float* qkv_b  = (const float*)d_in[2];
  const float* q_g    = (const float*)d_in[3];
  const float* q_b    = (const float*)d_in[4];
  const float* k_g    = (const float*)d_in[5];
  const float* k_b    = (const float*)d_in[6];
  const float* proj_w = (const float*)d_in[7];
  const float* proj_b = (const float*)d_in[8];

  const int M = in_sizes[0] / C_DIM;  // tokens = B*N
  const int Bb = M / 1024;

  // ws = region A (qkv_bf, M*3072 shorts) + region B (Qb|Kb|VT slots).
  // Total 48 MiB at M=4096 (round-3-proven). Overlays & lifetimes:
  //  pre-GEMM:  x_bf -> Qb slot, qw_bf -> Kb slot (dead after qkv GEMM)
  //  post-GEMM: prep writes Qb,Kb,VT (region B; VT source = qkv v-cols in A)
  //  attn: reads region B, writes AO = A[0,M*1024); tail blocks cast proj_w
  //        into pw_bf = A[2M,3M)*1024 (qkv dead by then; AO disjoint).
  const size_t required = (size_t)M * 3072 * 2 + (size_t)3 * M * 1024 * 2;
  if (ws_size < required) {
    sentinel_kernel<<<1, 64, 0, stream>>>((unsigned short*)d_out, (float)ws_size);
    return;
  }

  unsigned short* qkv_bf = (unsigned short*)d_ws;               // region A
  unsigned short* Qb = qkv_bf + (size_t)M * 3072;               // region B
  unsigned short* Kb = Qb + (size_t)M * 1024;
  unsigned short* VTn = Kb + (size_t)M * 1024;                  // former Vb slot
  unsigned short* x_bf = Qb;                                    // overlay
  unsigned short* qw_bf = Kb;                                   // overlay (3M<=4M)
  unsigned short* AO = qkv_bf;                                  // overlay
  unsigned short* pw_bf = qkv_bf + (size_t)2 * M * 1024;        // overlay

  const int n4x = M * 1024 / 4;
  const int n4w1 = 3072 * 1024 / 4;
  const int n4w2 = 1024 * 1024 / 4;

  cast2_kernel<<<(n4x + n4w1) / 256, 256, 0, stream>>>(
      x, qkv_w, x_bf, qw_bf, n4x);

  gemm_nt<true><<<(M / 128) * (3072 / 128), 256, 0, stream>>>(
      x_bf, qw_bf, qkv_b, qkv_bf, M / 128, M, 3072, 1024);

  prep_kernel<<<M + Bb * HEADS * 16, 256, 0, stream>>>(
      qkv_bf, q_g, q_b, k_g, k_b, Qb, Kb, VTn, M);

  const int nAttn = Bb * HEADS * 16;
  attn_kernel<<<nAttn + n4w2 / 256, 256, 0, stream>>>(
      Qb, Kb, VTn, AO, nAttn, proj_w, pw_bf);

  gemm_nt<false><<<(M / 128) * (1024 / 128), 256, 0, stream>>>(
      AO, pw_bf, proj_b, (float*)d_out, M / 128, M, 1024, 1024);
}